// Round 1
// baseline (1580.013 us; speedup 1.0000x reference)
//
#include <hip/hip_runtime.h>
#include <math.h>

// ---------------------------------------------------------------------------
// Fused transformer block w/ MoE (B=2,T=2048,C=1024,H=16,D=64,E=8,topK=2)
// Round 0: correctness-first, bf16 MFMA (16x16x32) for all GEMMs, routed MoE.
// ---------------------------------------------------------------------------

typedef __bf16 b16v8 __attribute__((ext_vector_type(8)));
typedef float f32x4 __attribute__((ext_vector_type(4)));

#define MFMA(a, b, c) __builtin_amdgcn_mfma_f32_16x16x32_bf16(a, b, c, 0, 0, 0)

constexpr int Bc = 2, Tc = 2048, Cc = 1024, Hc = 16, Dc = 64;
constexpr int Nc = Bc * Tc;       // 4096 tokens
constexpr int HIDc = 4096;        // 4*C
constexpr int Ec = 8;

__device__ inline unsigned short f32_bf16(float f) {
  union { float f; unsigned u; } x; x.f = f;
  unsigned r = x.u + 0x7fffu + ((x.u >> 16) & 1u);   // RNE
  return (unsigned short)(r >> 16);
}

__device__ inline float gelu_f(float x) {
  return 0.5f * x * (1.f + tanhf(0.7978845608028654f * (x + 0.044715f * x * x * x)));
}

// ---------------------------------------------------------------------------
// LayerNorm (f32 in -> bf16 out). One block per row, 256 threads.
// ---------------------------------------------------------------------------
__global__ __launch_bounds__(256) void ln1_kernel(
    const float* __restrict__ x, const float* __restrict__ g,
    const float* __restrict__ b, unsigned short* __restrict__ out) {
  const int row = blockIdx.x;
  const int tid = threadIdx.x;
  const float* xr = x + (size_t)row * Cc;
  float v[4]; float s = 0.f, q = 0.f;
#pragma unroll
  for (int j = 0; j < 4; ++j) { v[j] = xr[tid + j * 256]; s += v[j]; q += v[j] * v[j]; }
#pragma unroll
  for (int m = 1; m <= 32; m <<= 1) { s += __shfl_xor(s, m); q += __shfl_xor(q, m); }
  __shared__ float red[2][4];
  const int w = tid >> 6;
  if ((tid & 63) == 0) { red[0][w] = s; red[1][w] = q; }
  __syncthreads();
  s = red[0][0] + red[0][1] + red[0][2] + red[0][3];
  q = red[1][0] + red[1][1] + red[1][2] + red[1][3];
  const float mean = s * (1.f / Cc);
  const float var = q * (1.f / Cc) - mean * mean;
  const float rstd = rsqrtf(var + 1e-5f);
#pragma unroll
  for (int j = 0; j < 4; ++j) {
    int c = tid + j * 256;
    out[(size_t)row * Cc + c] = f32_bf16((v[j] - mean) * rstd * g[c] + b[c]);
  }
}

// ---------------------------------------------------------------------------
// LN2 + router (all-f32 router math to avoid top-k tie flips).
// Writes h2 (bf16) and per-token top-2 (expert idx + normalized gate).
// ---------------------------------------------------------------------------
__global__ __launch_bounds__(256) void ln2_router_kernel(
    const float* __restrict__ x, const float* __restrict__ g,
    const float* __restrict__ b, const float* __restrict__ rw,
    unsigned short* __restrict__ out, int* __restrict__ tki, float* __restrict__ tkp) {
  const int row = blockIdx.x;
  const int tid = threadIdx.x;
  const float* xr = x + (size_t)row * Cc;
  float v[4]; float s = 0.f, q = 0.f;
#pragma unroll
  for (int j = 0; j < 4; ++j) { v[j] = xr[tid + j * 256]; s += v[j]; q += v[j] * v[j]; }
#pragma unroll
  for (int m = 1; m <= 32; m <<= 1) { s += __shfl_xor(s, m); q += __shfl_xor(q, m); }
  __shared__ float red[2][4];
  const int w = tid >> 6;
  if ((tid & 63) == 0) { red[0][w] = s; red[1][w] = q; }
  __syncthreads();
  s = red[0][0] + red[0][1] + red[0][2] + red[0][3];
  q = red[1][0] + red[1][1] + red[1][2] + red[1][3];
  const float mean = s * (1.f / Cc);
  const float var = q * (1.f / Cc) - mean * mean;
  const float rstd = rsqrtf(var + 1e-5f);
  float lg[8] = {0.f, 0.f, 0.f, 0.f, 0.f, 0.f, 0.f, 0.f};
#pragma unroll
  for (int j = 0; j < 4; ++j) {
    int c = tid + j * 256;
    float nv = (v[j] - mean) * rstd * g[c] + b[c];
    out[(size_t)row * Cc + c] = f32_bf16(nv);
    const float* rwc = rw + c * 8;
#pragma unroll
    for (int e = 0; e < 8; ++e) lg[e] += nv * rwc[e];
  }
#pragma unroll
  for (int m = 1; m <= 32; m <<= 1) {
#pragma unroll
    for (int e = 0; e < 8; ++e) lg[e] += __shfl_xor(lg[e], m);
  }
  __shared__ float rl[4][8];
  if ((tid & 63) == 0) {
#pragma unroll
    for (int e = 0; e < 8; ++e) rl[w][e] = lg[e];
  }
  __syncthreads();
  if (tid == 0) {
    float L[8];
#pragma unroll
    for (int e = 0; e < 8; ++e) L[e] = rl[0][e] + rl[1][e] + rl[2][e] + rl[3][e];
    int i1 = 0;
    for (int e = 1; e < 8; ++e) if (L[e] > L[i1]) i1 = e;
    int i2 = (i1 == 0) ? 1 : 0;
    for (int e = 0; e < 8; ++e) if (e != i1 && L[e] > L[i2]) i2 = e;
    // softmax-then-renormalize == pairwise logistic weights
    float e2 = expf(L[i2] - L[i1]);
    float inv = 1.f / (1.f + e2);
    tki[row * 2] = i1; tki[row * 2 + 1] = i2;
    tkp[row * 2] = inv; tkp[row * 2 + 1] = e2 * inv;
  }
}

// ---------------------------------------------------------------------------
// Build per-expert token lists (order nondeterministic; results per token are
// order-independent, so output stays bit-deterministic).
// ---------------------------------------------------------------------------
__global__ __launch_bounds__(256) void route_build_kernel(
    const int* __restrict__ tki, const float* __restrict__ tkp,
    int* __restrict__ counts, int* __restrict__ toks, float* __restrict__ gates) {
  int n = blockIdx.x * 256 + threadIdx.x;
  if (n >= Nc) return;
#pragma unroll
  for (int kk = 0; kk < 2; ++kk) {
    int e = tki[n * 2 + kk];
    int slot = atomicAdd(&counts[e], 1);
    toks[e * Nc + slot] = n;
    gates[e * Nc + slot] = tkp[n * 2 + kk];
  }
}

// ---------------------------------------------------------------------------
// Generic 64x64-tile bf16 MFMA GEMM: C[M,N] = A[M,K](bf16) * B[K,N](f32->bf16)
// 4 waves per block, each wave owns a 32x32 quadrant (2x2 of 16x16x32 MFMA).
// MODE: 0=QKV scatter, 1=proj+residual->f32, 2=fc+gelu->bf16, 3=pj*gate +=f32
// ---------------------------------------------------------------------------
struct GArgs {
  const unsigned short* A;   // bf16
  const float* B;            // f32 [K][N]
  const float* bias;         // f32 [N]
  int M, N, K, lda;
  const int* Mptr;           // device row count (experts) or null
  const int* gatherA;        // MODE 2: token list for A rows
  const int* scatterRows;    // MODE 3: token list for output rows
  const float* gateList;     // MODE 3
  float* outF;               // MODE 1/3
  const float* resid;        // MODE 1
  unsigned short* outB;      // MODE 2: he ; MODE 0: q
  unsigned short* outK;      // MODE 0: k
  unsigned short* outV;      // MODE 0: v
};

template <int MODE>
__global__ __launch_bounds__(256) void gemm_kernel(GArgs g) {
  const int M = g.Mptr ? *g.Mptr : g.M;
  const int row0 = blockIdx.y * 64;
  if (row0 >= M) return;
  const int col0 = blockIdx.x * 64;
  __shared__ __align__(16) unsigned short ldsA[64][40];  // [m][k], pad 32->40
  __shared__ __align__(16) unsigned short ldsB[64][40];  // [n][k] (transposed)
  const int tid = threadIdx.x;
  const int lane = tid & 63;
  const int w = tid >> 6, wr = w >> 1, wc = w & 1;
  const int fr = lane & 15, fg = lane >> 4;
  f32x4 acc[2][2] = {};

  const int arow = tid >> 2;          // 0..63
  const int acol = (tid & 3) * 8;     // 0,8,16,24
  const bool aok = (row0 + arow) < M;
  size_t abase = 0;
  if (aok) {
    int r = row0 + arow;
    int src = r;
    if constexpr (MODE == 2) src = g.gatherA[r];
    abase = (size_t)src * g.lda + acol;
  }
  const int bn = tid & 63;
  const int bk4 = tid >> 6;           // 0..3
  const float* Bcol = g.B + col0 + bn;

  for (int k0 = 0; k0 < g.K; k0 += 32) {
    __syncthreads();
    uint4 av = {0u, 0u, 0u, 0u};
    if (aok) av = *(const uint4*)(g.A + abase + k0);
    *(uint4*)&ldsA[arow][acol] = av;
#pragma unroll
    for (int p = 0; p < 8; ++p) {
      int kk = p * 4 + bk4;
      float bv = Bcol[(size_t)(k0 + kk) * g.N];
      ldsB[bn][kk] = f32_bf16(bv);
    }
    __syncthreads();
    b16v8 a0 = *(const b16v8*)&ldsA[wr * 32 + fr][fg * 8];
    b16v8 a1 = *(const b16v8*)&ldsA[wr * 32 + 16 + fr][fg * 8];
    b16v8 b0 = *(const b16v8*)&ldsB[wc * 32 + fr][fg * 8];
    b16v8 b1 = *(const b16v8*)&ldsB[wc * 32 + 16 + fr][fg * 8];
    acc[0][0] = MFMA(a0, b0, acc[0][0]);
    acc[0][1] = MFMA(a0, b1, acc[0][1]);
    acc[1][0] = MFMA(a1, b0, acc[1][0]);
    acc[1][1] = MFMA(a1, b1, acc[1][1]);
  }

#pragma unroll
  for (int mi = 0; mi < 2; ++mi) {
#pragma unroll
    for (int ni = 0; ni < 2; ++ni) {
#pragma unroll
      for (int r = 0; r < 4; ++r) {
        int row = row0 + wr * 32 + mi * 16 + fg * 4 + r;   // D: row=(lane>>4)*4+reg
        int col = col0 + wc * 32 + ni * 16 + fr;           // D: col=lane&15
        if (row >= M) continue;
        float val = acc[mi][ni][r] + (g.bias ? g.bias[col] : 0.f);
        if constexpr (MODE == 0) {
          int bb = row >> 11, t = row & (Tc - 1);
          int which = col >> 10, cj = col & (Cc - 1);
          int hd = cj >> 6, d = cj & 63;
          unsigned short* dst = (which == 0) ? g.outB : (which == 1) ? g.outK : g.outV;
          dst[(((size_t)(bb * Hc + hd)) * Tc + t) * Dc + d] = f32_bf16(val);
        } else if constexpr (MODE == 1) {
          size_t o = (size_t)row * g.N + col;
          g.outF[o] = val + g.resid[o];
        } else if constexpr (MODE == 2) {
          g.outB[(size_t)row * g.N + col] = f32_bf16(gelu_f(val));
        } else {
          int tok = g.scatterRows[row];
          g.outF[(size_t)tok * Cc + col] += g.gateList[row] * val;
        }
      }
    }
  }
}

// ---------------------------------------------------------------------------
// Flash-style causal attention. Block = 4 waves, 64 q-rows (16 per wave).
// K tile LDS [kv][d]; V tile transposed LDS [d][kv]; P via per-wave LDS
// round-trip to reach the A-fragment layout.
// ---------------------------------------------------------------------------
__global__ __launch_bounds__(256) void attn_kernel(
    const unsigned short* __restrict__ q, const unsigned short* __restrict__ k,
    const unsigned short* __restrict__ v, unsigned short* __restrict__ y) {
  const int qt = blockIdx.x, bh = blockIdx.y;
  const int qbase = qt * 64;
  __shared__ __align__(16) unsigned short ldsK[64][72];
  __shared__ __align__(16) unsigned short ldsV[64][72];      // [d][kv]
  __shared__ __align__(16) unsigned short ldsP[4][16][72];
  const int tid = threadIdx.x, lane = tid & 63, w = tid >> 6;
  const int fr = lane & 15, fg = lane >> 4;
  const size_t base = (size_t)bh * Tc * Dc;
  const int qrow = qbase + w * 16 + fr;
  b16v8 qa0 = *(const b16v8*)(q + base + (size_t)qrow * Dc + fg * 8);
  b16v8 qa1 = *(const b16v8*)(q + base + (size_t)qrow * Dc + 32 + fg * 8);
  float m[4], lsum[4] = {0.f, 0.f, 0.f, 0.f};
#pragma unroll
  for (int r = 0; r < 4; ++r) m[r] = -3.0e38f;
  f32x4 oacc[4] = {};

  for (int kb = 0; kb <= qbase; kb += 64) {
    __syncthreads();
#pragma unroll
    for (int p2 = 0; p2 < 2; ++p2) {
      int idx = p2 * 256 + tid;
      int r = idx >> 3, cb = (idx & 7) * 8;
      uint4 kv4 = *(const uint4*)(k + base + (size_t)(kb + r) * Dc + cb);
      *(uint4*)&ldsK[r][cb] = kv4;
      uint4 vv4 = *(const uint4*)(v + base + (size_t)(kb + r) * Dc + cb);
      const unsigned short* vp = (const unsigned short*)&vv4;
#pragma unroll
      for (int j = 0; j < 8; ++j) ldsV[cb + j][r] = vp[j];
    }
    __syncthreads();

    f32x4 s[4];
#pragma unroll
    for (int ni = 0; ni < 4; ++ni) {
      b16v8 kb0 = *(const b16v8*)&ldsK[ni * 16 + fr][fg * 8];
      b16v8 kb1 = *(const b16v8*)&ldsK[ni * 16 + fr][32 + fg * 8];
      f32x4 z = {};
      z = MFMA(qa0, kb0, z);
      z = MFMA(qa1, kb1, z);
      s[ni] = z;
    }
    const bool diag = (kb == qbase);
#pragma unroll
    for (int ni = 0; ni < 4; ++ni) {
#pragma unroll
      for (int r = 0; r < 4; ++r) {
        float sv = s[ni][r] * 0.125f;   // 1/sqrt(64)
        if (diag) {
          int qr = w * 16 + fg * 4 + r;
          int kc = ni * 16 + fr;
          if (kc > qr) sv = -3.0e38f;
        }
        s[ni][r] = sv;
      }
    }
#pragma unroll
    for (int r = 0; r < 4; ++r) {
      float mx = fmaxf(fmaxf(s[0][r], s[1][r]), fmaxf(s[2][r], s[3][r]));
#pragma unroll
      for (int msk = 1; msk <= 8; msk <<= 1) mx = fmaxf(mx, __shfl_xor(mx, msk));
      float mnew = fmaxf(m[r], mx);
      float alpha = expf(m[r] - mnew);
      float psum = 0.f;
#pragma unroll
      for (int ni = 0; ni < 4; ++ni) {
        float pp = expf(s[ni][r] - mnew);
        s[ni][r] = pp;
        psum += pp;
      }
#pragma unroll
      for (int msk = 1; msk <= 8; msk <<= 1) psum += __shfl_xor(psum, msk);
      lsum[r] = lsum[r] * alpha + psum;
      m[r] = mnew;
#pragma unroll
      for (int ni = 0; ni < 4; ++ni) {
        oacc[ni][r] = oacc[ni][r] * alpha;
        ldsP[w][fg * 4 + r][ni * 16 + fr] = f32_bf16(s[ni][r]);
      }
    }
    // wave-synchronous LDS round-trip: drain ds ops, block scheduler motion
    asm volatile("s_waitcnt lgkmcnt(0)" ::: "memory");
    __builtin_amdgcn_sched_barrier(0);
    b16v8 pa0 = *(const b16v8*)&ldsP[w][fr][fg * 8];
    b16v8 pa1 = *(const b16v8*)&ldsP[w][fr][32 + fg * 8];
#pragma unroll
    for (int ni = 0; ni < 4; ++ni) {
      b16v8 vb0 = *(const b16v8*)&ldsV[ni * 16 + fr][fg * 8];
      b16v8 vb1 = *(const b16v8*)&ldsV[ni * 16 + fr][32 + fg * 8];
      oacc[ni] = MFMA(pa0, vb0, oacc[ni]);
      oacc[ni] = MFMA(pa1, vb1, oacc[ni]);
    }
  }

  const int bb = bh >> 4, hh = bh & 15;
#pragma unroll
  for (int ni = 0; ni < 4; ++ni) {
#pragma unroll
    for (int r = 0; r < 4; ++r) {
      int t = qbase + w * 16 + fg * 4 + r;
      int d = ni * 16 + fr;
      float val = oacc[ni][r] / lsum[r];
      y[((size_t)(bb * Tc + t)) * Cc + hh * Dc + d] = f32_bf16(val);
    }
  }
}

// ---------------------------------------------------------------------------
extern "C" void kernel_launch(void* const* d_in, const int* in_sizes, int n_in,
                              void* d_out, int out_size, void* d_ws, size_t ws_size,
                              hipStream_t stream) {
  const float* x       = (const float*)d_in[0];
  const float* ln1_g   = (const float*)d_in[1];
  const float* ln1_b   = (const float*)d_in[2];
  const float* ln2_g   = (const float*)d_in[3];
  const float* ln2_b   = (const float*)d_in[4];
  const float* attn_w  = (const float*)d_in[5];
  const float* attn_b  = (const float*)d_in[6];
  const float* proj_w  = (const float*)d_in[7];
  const float* proj_b  = (const float*)d_in[8];
  const float* router_w= (const float*)d_in[9];
  const float* fc_w    = (const float*)d_in[10];
  const float* fc_b    = (const float*)d_in[11];
  const float* pj_w    = (const float*)d_in[12];
  const float* pj_b    = (const float*)d_in[13];
  float* out = (float*)d_out;

  char* ws = (char*)d_ws;
  size_t off = 0;
  auto alloc = [&](size_t bytes) -> void* {
    void* p = ws + off;
    off = (off + bytes + 255) & ~(size_t)255;
    return p;
  };
  unsigned short* qb   = (unsigned short*)alloc((size_t)Nc * Cc * 2);   // [B,H,T,D]
  unsigned short* kbuf = (unsigned short*)alloc((size_t)Nc * Cc * 2);
  unsigned short* vbuf = (unsigned short*)alloc((size_t)Nc * Cc * 2);
  unsigned short* ybuf = (unsigned short*)alloc((size_t)Nc * Cc * 2);   // [N,C]
  unsigned short* h    = (unsigned short*)alloc((size_t)Nc * Cc * 2);   // ln1 out, reused as ln2 out
  unsigned short* he   = (unsigned short*)alloc((size_t)Nc * HIDc * 2); // expert hidden
  int*   tki    = (int*)alloc((size_t)Nc * 2 * 4);
  float* tkp    = (float*)alloc((size_t)Nc * 2 * 4);
  int*   counts = (int*)alloc(Ec * 4);
  int*   toks   = (int*)alloc((size_t)Ec * Nc * 4);
  float* gates  = (float*)alloc((size_t)Ec * Nc * 4);
  (void)ws_size; (void)in_sizes; (void)n_in; (void)out_size;

  // 1) LN1
  ln1_kernel<<<Nc, 256, 0, stream>>>(x, ln1_g, ln1_b, h);

  // 2) QKV GEMM -> q/k/v [B,H,T,D] bf16
  {
    GArgs a = {};
    a.A = h; a.B = attn_w; a.bias = attn_b;
    a.M = Nc; a.N = 3 * Cc; a.K = Cc; a.lda = Cc;
    a.outB = qb; a.outK = kbuf; a.outV = vbuf;
    gemm_kernel<0><<<dim3(48, 64), 256, 0, stream>>>(a);
  }

  // 3) causal attention -> y [N,C] bf16
  attn_kernel<<<dim3(Tc / 64, Bc * Hc), 256, 0, stream>>>(qb, kbuf, vbuf, ybuf);

  // 4) proj + residual -> d_out (f32)
  {
    GArgs p = {};
    p.A = ybuf; p.B = proj_w; p.bias = proj_b;
    p.M = Nc; p.N = Cc; p.K = Cc; p.lda = Cc;
    p.outF = out; p.resid = x;
    gemm_kernel<1><<<dim3(16, 64), 256, 0, stream>>>(p);
  }

  // 5) LN2 + router (f32 router math) -> h (bf16), top-2
  ln2_router_kernel<<<Nc, 256, 0, stream>>>(out, ln2_g, ln2_b, router_w, h, tki, tkp);

  // 6) routing lists
  hipMemsetAsync(counts, 0, Ec * sizeof(int), stream);
  route_build_kernel<<<(Nc + 255) / 256, 256, 0, stream>>>(tki, tkp, counts, toks, gates);

  // 7) experts, sequential (race-free scatter-add into d_out)
  for (int e = 0; e < Ec; ++e) {
    GArgs f = {};
    f.A = h; f.B = fc_w + (size_t)e * Cc * HIDc; f.bias = fc_b + (size_t)e * HIDc;
    f.M = Nc; f.N = HIDc; f.K = Cc; f.lda = Cc;
    f.Mptr = counts + e; f.gatherA = toks + e * Nc;
    f.outB = he;
    gemm_kernel<2><<<dim3(HIDc / 64, Nc / 64), 256, 0, stream>>>(f);

    GArgs pj = {};
    pj.A = he; pj.B = pj_w + (size_t)e * HIDc * Cc; pj.bias = pj_b + (size_t)e * Cc;
    pj.M = Nc; pj.N = Cc; pj.K = HIDc; pj.lda = HIDc;
    pj.Mptr = counts + e; pj.scatterRows = toks + e * Nc; pj.gateList = gates + e * Nc;
    pj.outF = out;
    gemm_kernel<3><<<dim3(Cc / 64, Nc / 64), 256, 0, stream>>>(pj);
  }
}

// Round 2
// 731.234 us; speedup vs baseline: 2.1607x; 2.1607x over previous
//
#include <hip/hip_runtime.h>
#include <math.h>

// ---------------------------------------------------------------------------
// Fused transformer block w/ MoE (B=2,T=2048,C=1024,H=16,D=64,E=8,topK=2)
// Round 2: bf16 weight pre-transpose, m97-structure 128^2 GEMM w/
// global_load_lds(16B), concurrent experts via slot compaction, attn exp2 +
// pre-transposed V.
// ---------------------------------------------------------------------------

typedef __bf16 b16v8 __attribute__((ext_vector_type(8)));
typedef float f32x4 __attribute__((ext_vector_type(4)));

#define MFMA(a, b, c) __builtin_amdgcn_mfma_f32_16x16x32_bf16(a, b, c, 0, 0, 0)

#define GLOAD_LDS16(g, l)                                          \
  __builtin_amdgcn_global_load_lds(                                \
      (const __attribute__((address_space(1))) void*)(g),          \
      (__attribute__((address_space(3))) void*)(l), 16, 0, 0)

constexpr int Bc = 2, Tc = 2048, Cc = 1024, Hc = 16, Dc = 64;
constexpr int Nc = Bc * Tc;       // 4096 tokens
constexpr int HIDc = 4096;        // 4*C
constexpr int Ec = 8;
constexpr int NPAIR = Nc * 2;     // 8192 (always: top-2 per token)
constexpr float LOG2E = 1.4426950408889634f;

__device__ inline unsigned short f32_bf16(float f) {
  union { float f; unsigned u; } x; x.f = f;
  unsigned r = x.u + 0x7fffu + ((x.u >> 16) & 1u);   // RNE
  return (unsigned short)(r >> 16);
}

__device__ inline float gelu_f(float x) {
  return 0.5f * x * (1.f + tanhf(0.7978845608028654f * (x + 0.044715f * x * x * x)));
}

// ---------------------------------------------------------------------------
// Transpose+convert: src f32 [batch][K][N] -> dst bf16 [batch][N][K]
// ---------------------------------------------------------------------------
__global__ __launch_bounds__(256) void convT_kernel(
    const float* __restrict__ src, unsigned short* __restrict__ dst,
    int K, int N) {
  const size_t sb = (size_t)blockIdx.z * K * N;
  const int n0 = blockIdx.x * 32, k0 = blockIdx.y * 32;
  __shared__ float t[32][33];
  const int tx = threadIdx.x & 31, ty = threadIdx.x >> 5;  // ty 0..7
#pragma unroll
  for (int j = 0; j < 4; ++j)
    t[ty + j * 8][tx] = src[sb + (size_t)(k0 + ty + j * 8) * N + n0 + tx];
  __syncthreads();
#pragma unroll
  for (int j = 0; j < 4; ++j)
    dst[sb + (size_t)(n0 + ty + j * 8) * K + k0 + tx] = f32_bf16(t[tx][ty + j * 8]);
}

// ---------------------------------------------------------------------------
// LayerNorm (f32 in -> bf16 out). One block per row, 256 threads.
// ---------------------------------------------------------------------------
__global__ __launch_bounds__(256) void ln1_kernel(
    const float* __restrict__ x, const float* __restrict__ g,
    const float* __restrict__ b, unsigned short* __restrict__ out) {
  const int row = blockIdx.x;
  const int tid = threadIdx.x;
  const float* xr = x + (size_t)row * Cc;
  float v[4]; float s = 0.f, q = 0.f;
#pragma unroll
  for (int j = 0; j < 4; ++j) { v[j] = xr[tid + j * 256]; s += v[j]; q += v[j] * v[j]; }
#pragma unroll
  for (int m = 1; m <= 32; m <<= 1) { s += __shfl_xor(s, m); q += __shfl_xor(q, m); }
  __shared__ float red[2][4];
  const int w = tid >> 6;
  if ((tid & 63) == 0) { red[0][w] = s; red[1][w] = q; }
  __syncthreads();
  s = red[0][0] + red[0][1] + red[0][2] + red[0][3];
  q = red[1][0] + red[1][1] + red[1][2] + red[1][3];
  const float mean = s * (1.f / Cc);
  const float var = q * (1.f / Cc) - mean * mean;
  const float rstd = rsqrtf(var + 1e-5f);
#pragma unroll
  for (int j = 0; j < 4; ++j) {
    int c = tid + j * 256;
    out[(size_t)row * Cc + c] = f32_bf16((v[j] - mean) * rstd * g[c] + b[c]);
  }
}

// ---------------------------------------------------------------------------
// LN2 + router (all-f32 router math to avoid top-k tie flips).
// ---------------------------------------------------------------------------
__global__ __launch_bounds__(256) void ln2_router_kernel(
    const float* __restrict__ x, const float* __restrict__ g,
    const float* __restrict__ b, const float* __restrict__ rw,
    unsigned short* __restrict__ out, int* __restrict__ tki, float* __restrict__ tkp) {
  const int row = blockIdx.x;
  const int tid = threadIdx.x;
  const float* xr = x + (size_t)row * Cc;
  float v[4]; float s = 0.f, q = 0.f;
#pragma unroll
  for (int j = 0; j < 4; ++j) { v[j] = xr[tid + j * 256]; s += v[j]; q += v[j] * v[j]; }
#pragma unroll
  for (int m = 1; m <= 32; m <<= 1) { s += __shfl_xor(s, m); q += __shfl_xor(q, m); }
  __shared__ float red[2][4];
  const int w = tid >> 6;
  if ((tid & 63) == 0) { red[0][w] = s; red[1][w] = q; }
  __syncthreads();
  s = red[0][0] + red[0][1] + red[0][2] + red[0][3];
  q = red[1][0] + red[1][1] + red[1][2] + red[1][3];
  const float mean = s * (1.f / Cc);
  const float var = q * (1.f / Cc) - mean * mean;
  const float rstd = rsqrtf(var + 1e-5f);
  float lg[8] = {0.f, 0.f, 0.f, 0.f, 0.f, 0.f, 0.f, 0.f};
#pragma unroll
  for (int j = 0; j < 4; ++j) {
    int c = tid + j * 256;
    float nv = (v[j] - mean) * rstd * g[c] + b[c];
    out[(size_t)row * Cc + c] = f32_bf16(nv);
    const float* rwc = rw + c * 8;
#pragma unroll
    for (int e = 0; e < 8; ++e) lg[e] += nv * rwc[e];
  }
#pragma unroll
  for (int m = 1; m <= 32; m <<= 1) {
#pragma unroll
    for (int e = 0; e < 8; ++e) lg[e] += __shfl_xor(lg[e], m);
  }
  __shared__ float rl[4][8];
  if ((tid & 63) == 0) {
#pragma unroll
    for (int e = 0; e < 8; ++e) rl[w][e] = lg[e];
  }
  __syncthreads();
  if (tid == 0) {
    float L[8];
#pragma unroll
    for (int e = 0; e < 8; ++e) L[e] = rl[0][e] + rl[1][e] + rl[2][e] + rl[3][e];
    int i1 = 0;
    for (int e = 1; e < 8; ++e) if (L[e] > L[i1]) i1 = e;
    int i2 = (i1 == 0) ? 1 : 0;
    for (int e = 0; e < 8; ++e) if (e != i1 && L[e] > L[i2]) i2 = e;
    float e2 = expf(L[i2] - L[i1]);
    float inv = 1.f / (1.f + e2);
    tki[row * 2] = i1; tki[row * 2 + 1] = i2;
    tkp[row * 2] = inv; tkp[row * 2 + 1] = e2 * inv;
  }
}

// ---------------------------------------------------------------------------
// Routing: counts -> offsets -> slot assignment (slots compact by expert).
// Slot permutation is atomic-order dependent but per-token arithmetic is
// identical regardless of slot index -> output deterministic.
// ---------------------------------------------------------------------------
__global__ __launch_bounds__(256) void count_kernel(
    const int* __restrict__ tki, int* __restrict__ counts) {
  int n = blockIdx.x * 256 + threadIdx.x;
  if (n >= Nc) return;
  atomicAdd(&counts[tki[n * 2]], 1);
  atomicAdd(&counts[tki[n * 2 + 1]], 1);
}

__global__ void scan_kernel(const int* __restrict__ counts,
                            int* __restrict__ eoff, int* __restrict__ cursor) {
  if (threadIdx.x == 0 && blockIdx.x == 0) {
    int s = 0;
    for (int e = 0; e < Ec; ++e) { eoff[e] = s; cursor[e] = s; s += counts[e]; }
    eoff[Ec] = s;
  }
}

__global__ __launch_bounds__(256) void assign_kernel(
    const int* __restrict__ tki, int* __restrict__ cursor,
    int* __restrict__ slot_tok, int* __restrict__ tok2slot) {
  int n = blockIdx.x * 256 + threadIdx.x;
  if (n >= Nc) return;
#pragma unroll
  for (int kk = 0; kk < 2; ++kk) {
    int e = tki[n * 2 + kk];
    int slot = atomicAdd(&cursor[e], 1);
    slot_tok[slot] = n;
    tok2slot[n * 2 + kk] = slot;
  }
}

// ---------------------------------------------------------------------------
// m97-structure GEMM: 128x128 tile, BK=32, 4 waves x (4x4) 16x16x32 frags.
// A bf16 [M][lda] (optionally row-gathered), B bf16 pre-transposed [N][K].
// MODE: 0=QKV scatter (V transposed), 1=proj+residual->f32,
//       2=fc gather +gelu->he(bf16), 3=pj->pairout(f32)
// ---------------------------------------------------------------------------
struct GArgs {
  const unsigned short* A;    // bf16
  const unsigned short* Bt;   // bf16 [N][K] (+ e*Bstride)
  const float* bias;          // f32 [N]     (+ e*biasStride)
  int M, N, K, lda;
  size_t Bstride; int biasStride;
  const int* eoff;            // [E+1] slot offsets (MODE 2/3)
  const int* slot_tok;        // slot -> token (MODE 2)
  float* outF;                // MODE 1: out, MODE 3: pairout
  const float* resid;         // MODE 1
  unsigned short* outB;       // MODE 2: he ; MODE 0: q
  unsigned short* outK;       // MODE 0: k
  unsigned short* outV;       // MODE 0: v^T [B,H,D,T]
};

template <int MODE>
__global__ __launch_bounds__(256) void gemm128(GArgs g) {
  const int e = blockIdx.z;
  int s0 = 0, Meff = g.M;
  if constexpr (MODE == 2 || MODE == 3) {
    s0 = g.eoff[e];
    Meff = g.eoff[e + 1] - s0;
  }
  const int row0 = blockIdx.y * 128;
  if (row0 >= Meff) return;
  const int col0 = blockIdx.x * 128;

  __shared__ __align__(16) unsigned short As[128 * 32];
  __shared__ __align__(16) unsigned short Bs[128 * 32];

  const int tid = threadIdx.x;
  const int lane = tid & 63, w = tid >> 6;
  const int wr = w >> 1, wc = w & 1;
  const int fr = lane & 15, fg = lane >> 4;

  const unsigned short* Bt = g.Bt + (size_t)e * g.Bstride;
  const float* bias = g.bias + (size_t)e * g.biasStride;

  // per-issue global addresses (element offsets), k0 added in loop
  size_t aaddr[2], baddr[2];
#pragma unroll
  for (int i = 0; i < 2; ++i) {
    int pos = i * 256 + tid;
    int r = pos >> 2, c8 = (pos & 3) * 8;
    int gr = row0 + r;
    if (gr >= Meff) gr = Meff - 1;            // clamp (partial expert tiles)
    int srcrow;
    if constexpr (MODE == 2) srcrow = g.slot_tok[s0 + gr];
    else if constexpr (MODE == 3) srcrow = s0 + gr;
    else srcrow = gr;
    aaddr[i] = (size_t)srcrow * g.lda + c8;
    int n = pos >> 2;
    baddr[i] = (size_t)(col0 + n) * g.K + c8;
  }

  f32x4 acc[4][4] = {};

  for (int k0 = 0; k0 < g.K; k0 += 32) {
    __syncthreads();
#pragma unroll
    for (int i = 0; i < 2; ++i) {
      GLOAD_LDS16(g.A + aaddr[i] + k0, As + (size_t)(i * 2048 + w * 512));
      GLOAD_LDS16(Bt + baddr[i] + k0,  Bs + (size_t)(i * 2048 + w * 512));
    }
    __syncthreads();
    b16v8 af[4], bf_[4];
#pragma unroll
    for (int mi = 0; mi < 4; ++mi)
      af[mi] = *(const b16v8*)&As[(wr * 64 + mi * 16 + fr) * 32 + fg * 8];
#pragma unroll
    for (int ni = 0; ni < 4; ++ni)
      bf_[ni] = *(const b16v8*)&Bs[(wc * 64 + ni * 16 + fr) * 32 + fg * 8];
#pragma unroll
    for (int mi = 0; mi < 4; ++mi)
#pragma unroll
      for (int ni = 0; ni < 4; ++ni)
        acc[mi][ni] = MFMA(af[mi], bf_[ni], acc[mi][ni]);
  }

#pragma unroll
  for (int mi = 0; mi < 4; ++mi) {
#pragma unroll
    for (int ni = 0; ni < 4; ++ni) {
#pragma unroll
      for (int rr = 0; rr < 4; ++rr) {
        int row = row0 + wr * 64 + mi * 16 + fg * 4 + rr;  // D: row=(lane>>4)*4+reg
        int col = col0 + wc * 64 + ni * 16 + fr;           // D: col=lane&15
        if (row >= Meff) continue;
        float val = acc[mi][ni][rr] + bias[col];
        if constexpr (MODE == 0) {
          int bb = row >> 11, t = row & (Tc - 1);
          int which = col >> 10, cj = col & (Cc - 1);
          int hd = cj >> 6, d = cj & 63;
          if (which == 0)
            g.outB[(((size_t)(bb * Hc + hd)) * Tc + t) * Dc + d] = f32_bf16(val);
          else if (which == 1)
            g.outK[(((size_t)(bb * Hc + hd)) * Tc + t) * Dc + d] = f32_bf16(val);
          else
            g.outV[(((size_t)(bb * Hc + hd)) * Dc + d) * Tc + t] = f32_bf16(val);
        } else if constexpr (MODE == 1) {
          size_t o = (size_t)row * g.N + col;
          g.outF[o] = val + g.resid[o];
        } else if constexpr (MODE == 2) {
          g.outB[(size_t)(s0 + row) * g.N + col] = f32_bf16(gelu_f(val));
        } else {
          g.outF[(size_t)(s0 + row) * g.N + col] = val;
        }
      }
    }
  }
}

// ---------------------------------------------------------------------------
// Flash-style causal attention. Block = 4 waves, 64 q-rows (16 per wave).
// K tile LDS [kv][d]; V^T tile LDS [d][kv] loaded from pre-transposed vbuf.
// Softmax in exp2 domain. P via per-wave LDS round-trip.
// ---------------------------------------------------------------------------
__global__ __launch_bounds__(256) void attn_kernel(
    const unsigned short* __restrict__ q, const unsigned short* __restrict__ k,
    const unsigned short* __restrict__ v, unsigned short* __restrict__ y) {
  const int qt = blockIdx.x, bh = blockIdx.y;
  const int qbase = qt * 64;
  __shared__ __align__(16) unsigned short ldsK[64][72];
  __shared__ __align__(16) unsigned short ldsVT[64][72];     // [d][kv]
  __shared__ __align__(16) unsigned short ldsP[4][16][72];
  const int tid = threadIdx.x, lane = tid & 63, w = tid >> 6;
  const int fr = lane & 15, fg = lane >> 4;
  const size_t base = (size_t)bh * Tc * Dc;
  const int qrow = qbase + w * 16 + fr;
  b16v8 qa0 = *(const b16v8*)(q + base + (size_t)qrow * Dc + fg * 8);
  b16v8 qa1 = *(const b16v8*)(q + base + (size_t)qrow * Dc + 32 + fg * 8);
  float m[4], lsum[4] = {0.f, 0.f, 0.f, 0.f};
#pragma unroll
  for (int r = 0; r < 4; ++r) m[r] = -3.0e38f;
  f32x4 oacc[4] = {};
  constexpr float SC = 0.125f * LOG2E;   // (1/sqrt(64)) * log2(e)

  for (int kb = 0; kb <= qbase; kb += 64) {
    __syncthreads();
#pragma unroll
    for (int i = 0; i < 2; ++i) {
      int pos = i * 256 + tid;
      int r = pos >> 3, cb = (pos & 7) * 8;
      *(uint4*)&ldsK[r][cb]  = *(const uint4*)(k + base + (size_t)(kb + r) * Dc + cb);
      *(uint4*)&ldsVT[r][cb] = *(const uint4*)(v + base + (size_t)r * Tc + kb + cb);
    }
    __syncthreads();

    f32x4 s[4];
#pragma unroll
    for (int ni = 0; ni < 4; ++ni) {
      b16v8 kb0 = *(const b16v8*)&ldsK[ni * 16 + fr][fg * 8];
      b16v8 kb1 = *(const b16v8*)&ldsK[ni * 16 + fr][32 + fg * 8];
      f32x4 z = {};
      z = MFMA(qa0, kb0, z);
      z = MFMA(qa1, kb1, z);
      s[ni] = z;
    }
    const bool diag = (kb == qbase);
#pragma unroll
    for (int ni = 0; ni < 4; ++ni) {
#pragma unroll
      for (int r = 0; r < 4; ++r) {
        float sv = s[ni][r] * SC;       // log2-domain scores
        if (diag) {
          int qr = w * 16 + fg * 4 + r;
          int kc = ni * 16 + fr;
          if (kc > qr) sv = -3.0e38f;
        }
        s[ni][r] = sv;
      }
    }
#pragma unroll
    for (int r = 0; r < 4; ++r) {
      float mx = fmaxf(fmaxf(s[0][r], s[1][r]), fmaxf(s[2][r], s[3][r]));
#pragma unroll
      for (int msk = 1; msk <= 8; msk <<= 1) mx = fmaxf(mx, __shfl_xor(mx, msk));
      float mnew = fmaxf(m[r], mx);
      float alpha = exp2f(m[r] - mnew);
      float psum = 0.f;
#pragma unroll
      for (int ni = 0; ni < 4; ++ni) {
        float pp = exp2f(s[ni][r] - mnew);
        s[ni][r] = pp;
        psum += pp;
      }
#pragma unroll
      for (int msk = 1; msk <= 8; msk <<= 1) psum += __shfl_xor(psum, msk);
      lsum[r] = lsum[r] * alpha + psum;
      m[r] = mnew;
#pragma unroll
      for (int ni = 0; ni < 4; ++ni) {
        oacc[ni][r] = oacc[ni][r] * alpha;
        ldsP[w][fg * 4 + r][ni * 16 + fr] = f32_bf16(s[ni][r]);
      }
    }
    asm volatile("s_waitcnt lgkmcnt(0)" ::: "memory");
    __builtin_amdgcn_sched_barrier(0);
    b16v8 pa0 = *(const b16v8*)&ldsP[w][fr][fg * 8];
    b16v8 pa1 = *(const b16v8*)&ldsP[w][fr][32 + fg * 8];
#pragma unroll
    for (int ni = 0; ni < 4; ++ni) {
      b16v8 vb0 = *(const b16v8*)&ldsVT[ni * 16 + fr][fg * 8];
      b16v8 vb1 = *(const b16v8*)&ldsVT[ni * 16 + fr][32 + fg * 8];
      oacc[ni] = MFMA(pa0, vb0, oacc[ni]);
      oacc[ni] = MFMA(pa1, vb1, oacc[ni]);
    }
  }

  const int bb = bh >> 4, hh = bh & 15;
#pragma unroll
  for (int ni = 0; ni < 4; ++ni) {
#pragma unroll
    for (int r = 0; r < 4; ++r) {
      int t = qbase + w * 16 + fg * 4 + r;
      int d = ni * 16 + fr;
      float val = oacc[ni][r] / lsum[r];
      y[((size_t)(bb * Tc + t)) * Cc + hh * Dc + d] = f32_bf16(val);
    }
  }
}

// ---------------------------------------------------------------------------
// Deterministic MoE combine: out[n] += p0*pair[s0] + p1*pair[s1]
// ---------------------------------------------------------------------------
__global__ __launch_bounds__(256) void combine_kernel(
    const float* __restrict__ pair, const float* __restrict__ tkp,
    const int* __restrict__ tok2slot, float* __restrict__ out) {
  const int n = blockIdx.x;
  const int c4 = threadIdx.x * 4;
  const int s0 = tok2slot[n * 2], s1 = tok2slot[n * 2 + 1];
  const float p0 = tkp[n * 2], p1 = tkp[n * 2 + 1];
  float4 a = *(const float4*)&pair[(size_t)s0 * Cc + c4];
  float4 b = *(const float4*)&pair[(size_t)s1 * Cc + c4];
  float4 o = *(float4*)&out[(size_t)n * Cc + c4];
  o.x += p0 * a.x + p1 * b.x;
  o.y += p0 * a.y + p1 * b.y;
  o.z += p0 * a.z + p1 * b.z;
  o.w += p0 * a.w + p1 * b.w;
  *(float4*)&out[(size_t)n * Cc + c4] = o;
}

// ---------------------------------------------------------------------------
extern "C" void kernel_launch(void* const* d_in, const int* in_sizes, int n_in,
                              void* d_out, int out_size, void* d_ws, size_t ws_size,
                              hipStream_t stream) {
  const float* x        = (const float*)d_in[0];
  const float* ln1_g    = (const float*)d_in[1];
  const float* ln1_b    = (const float*)d_in[2];
  const float* ln2_g    = (const float*)d_in[3];
  const float* ln2_b    = (const float*)d_in[4];
  const float* attn_w   = (const float*)d_in[5];
  const float* attn_b   = (const float*)d_in[6];
  const float* proj_w   = (const float*)d_in[7];
  const float* proj_b   = (const float*)d_in[8];
  const float* router_w = (const float*)d_in[9];
  const float* fc_w     = (const float*)d_in[10];
  const float* fc_b     = (const float*)d_in[11];
  const float* pj_w     = (const float*)d_in[12];
  const float* pj_b     = (const float*)d_in[13];
  float* out = (float*)d_out;

  char* ws = (char*)d_ws;
  size_t off = 0;
  auto alloc = [&](size_t bytes) -> void* {
    void* p = ws + off;
    off = (off + bytes + 255) & ~(size_t)255;
    return p;
  };
  unsigned short* attn_wT = (unsigned short*)alloc((size_t)3 * Cc * Cc * 2);      // [3C][C]
  unsigned short* proj_wT = (unsigned short*)alloc((size_t)Cc * Cc * 2);          // [C][C]
  unsigned short* fc_wT   = (unsigned short*)alloc((size_t)Ec * HIDc * Cc * 2);   // [E][HID][C]
  unsigned short* pj_wT   = (unsigned short*)alloc((size_t)Ec * Cc * HIDc * 2);   // [E][C][HID]
  unsigned short* h    = (unsigned short*)alloc((size_t)Nc * Cc * 2);
  unsigned short* qb   = (unsigned short*)alloc((size_t)Nc * Cc * 2);   // [B,H,T,D]
  unsigned short* kbuf = (unsigned short*)alloc((size_t)Nc * Cc * 2);   // [B,H,T,D]
  unsigned short* vbuf = (unsigned short*)alloc((size_t)Nc * Cc * 2);   // [B,H,D,T]
  unsigned short* ybuf = (unsigned short*)alloc((size_t)Nc * Cc * 2);   // [N,C]
  unsigned short* he   = (unsigned short*)alloc((size_t)NPAIR * HIDc * 2);
  float* pairout = (float*)alloc((size_t)NPAIR * Cc * 4);
  int*   tki     = (int*)alloc((size_t)Nc * 2 * 4);
  float* tkp     = (float*)alloc((size_t)Nc * 2 * 4);
  int*   counts  = (int*)alloc(Ec * 4);
  int*   eoff    = (int*)alloc((Ec + 1) * 4);
  int*   cursor  = (int*)alloc(Ec * 4);
  int*   slot_tok= (int*)alloc((size_t)NPAIR * 4);
  int*   tok2slot= (int*)alloc((size_t)Nc * 2 * 4);
  (void)ws_size; (void)in_sizes; (void)n_in; (void)out_size;

  // 0) weight pre-transpose/convert (independent of everything else)
  convT_kernel<<<dim3(3 * Cc / 32, Cc / 32, 1), 256, 0, stream>>>(attn_w, attn_wT, Cc, 3 * Cc);
  convT_kernel<<<dim3(Cc / 32, Cc / 32, 1), 256, 0, stream>>>(proj_w, proj_wT, Cc, Cc);
  convT_kernel<<<dim3(HIDc / 32, Cc / 32, Ec), 256, 0, stream>>>(fc_w, fc_wT, Cc, HIDc);
  convT_kernel<<<dim3(Cc / 32, HIDc / 32, Ec), 256, 0, stream>>>(pj_w, pj_wT, HIDc, Cc);

  // 1) LN1
  ln1_kernel<<<Nc, 256, 0, stream>>>(x, ln1_g, ln1_b, h);

  // 2) QKV GEMM -> q/k [B,H,T,D], v^T [B,H,D,T]
  {
    GArgs a = {};
    a.A = h; a.Bt = attn_wT; a.bias = attn_b;
    a.M = Nc; a.N = 3 * Cc; a.K = Cc; a.lda = Cc;
    a.outB = qb; a.outK = kbuf; a.outV = vbuf;
    gemm128<0><<<dim3(3 * Cc / 128, Nc / 128, 1), 256, 0, stream>>>(a);
  }

  // 3) causal attention -> y [N,C] bf16
  attn_kernel<<<dim3(Tc / 64, Bc * Hc), 256, 0, stream>>>(qb, kbuf, vbuf, ybuf);

  // 4) proj + residual -> d_out (f32)
  {
    GArgs p = {};
    p.A = ybuf; p.Bt = proj_wT; p.bias = proj_b;
    p.M = Nc; p.N = Cc; p.K = Cc; p.lda = Cc;
    p.outF = out; p.resid = x;
    gemm128<1><<<dim3(Cc / 128, Nc / 128, 1), 256, 0, stream>>>(p);
  }

  // 5) LN2 + router -> h (bf16), top-2
  ln2_router_kernel<<<Nc, 256, 0, stream>>>(out, ln2_g, ln2_b, router_w, h, tki, tkp);

  // 6) routing lists (slot-compacted pairs)
  hipMemsetAsync(counts, 0, Ec * sizeof(int), stream);
  count_kernel<<<(Nc + 255) / 256, 256, 0, stream>>>(tki, counts);
  scan_kernel<<<1, 64, 0, stream>>>(counts, eoff, cursor);
  assign_kernel<<<(Nc + 255) / 256, 256, 0, stream>>>(tki, cursor, slot_tok, tok2slot);

  // 7) fc (all experts concurrent) -> he [NPAIR][HID] bf16 w/ GELU
  {
    GArgs f = {};
    f.A = h; f.Bt = fc_wT; f.bias = fc_b;
    f.M = Nc; f.N = HIDc; f.K = Cc; f.lda = Cc;
    f.Bstride = (size_t)HIDc * Cc; f.biasStride = HIDc;
    f.eoff = eoff; f.slot_tok = slot_tok;
    f.outB = he;
    gemm128<2><<<dim3(HIDc / 128, Nc / 128, Ec), 256, 0, stream>>>(f);
  }

  // 8) pj (all experts concurrent) -> pairout [NPAIR][C] f32 (bias incl.)
  {
    GArgs pj = {};
    pj.A = he; pj.Bt = pj_wT; pj.bias = pj_b;
    pj.M = Nc; pj.N = Cc; pj.K = HIDc; pj.lda = HIDc;
    pj.Bstride = (size_t)Cc * HIDc; pj.biasStride = Cc;
    pj.eoff = eoff;
    pj.outF = pairout;
    gemm128<3><<<dim3(Cc / 128, Nc / 128, Ec), 256, 0, stream>>>(pj);
  }

  // 9) deterministic combine into d_out
  combine_kernel<<<Nc, 256, 0, stream>>>(pairout, tkp, tok2slot, out);
}

// Round 3
// 681.720 us; speedup vs baseline: 2.3177x; 1.0726x over previous
//
#include <hip/hip_runtime.h>
#include <math.h>

// ---------------------------------------------------------------------------
// Fused transformer block w/ MoE (B=2,T=2048,C=1024,H=16,D=64,E=8,topK=2)
// Round 3: double-buffered 2-phase K-loop (counted-drain + raw s_barrier,
// prefetch stays in flight during MFMA), exp2-based gelu/softmax.
// ---------------------------------------------------------------------------

typedef __bf16 b16v8 __attribute__((ext_vector_type(8)));
typedef float f32x4 __attribute__((ext_vector_type(4)));

#define MFMA(a, b, c) __builtin_amdgcn_mfma_f32_16x16x32_bf16(a, b, c, 0, 0, 0)

#define GLOAD_LDS16(g, l)                                          \
  __builtin_amdgcn_global_load_lds(                                \
      (const __attribute__((address_space(1))) void*)(g),          \
      (__attribute__((address_space(3))) void*)(l), 16, 0, 0)

// raw barrier with manual vmcnt drain; memory-clobber fences on both sides
#define SYNC_VM0()                                       \
  do {                                                   \
    asm volatile("s_waitcnt vmcnt(0)" ::: "memory");     \
    __builtin_amdgcn_s_barrier();                        \
    asm volatile("" ::: "memory");                       \
  } while (0)

constexpr int Bc = 2, Tc = 2048, Cc = 1024, Hc = 16, Dc = 64;
constexpr int Nc = Bc * Tc;       // 4096 tokens
constexpr int HIDc = 4096;        // 4*C
constexpr int Ec = 8;
constexpr int NPAIR = Nc * 2;     // 8192 (always: top-2 per token)
constexpr float LOG2E = 1.4426950408889634f;

__device__ inline unsigned short f32_bf16(float f) {
  union { float f; unsigned u; } x; x.f = f;
  unsigned r = x.u + 0x7fffu + ((x.u >> 16) & 1u);   // RNE
  return (unsigned short)(r >> 16);
}

// gelu(x) = x * sigmoid(1.595769122*(x+0.044715x^3));  exp2-domain, 1 exp + 1 rcp
__device__ inline float gelu_f(float x) {
  float t = 2.3021188f * x * (1.f + 0.044715f * x * x);   // 1.5957691*log2(e)
  float e = __builtin_amdgcn_exp2f(-t);
  return x * __builtin_amdgcn_rcpf(1.f + e);
}

// ---------------------------------------------------------------------------
// Transpose+convert: src f32 [batch][K][N] -> dst bf16 [batch][N][K]
// ---------------------------------------------------------------------------
__global__ __launch_bounds__(256) void convT_kernel(
    const float* __restrict__ src, unsigned short* __restrict__ dst,
    int K, int N) {
  const size_t sb = (size_t)blockIdx.z * K * N;
  const int n0 = blockIdx.x * 32, k0 = blockIdx.y * 32;
  __shared__ float t[32][33];
  const int tx = threadIdx.x & 31, ty = threadIdx.x >> 5;  // ty 0..7
#pragma unroll
  for (int j = 0; j < 4; ++j)
    t[ty + j * 8][tx] = src[sb + (size_t)(k0 + ty + j * 8) * N + n0 + tx];
  __syncthreads();
#pragma unroll
  for (int j = 0; j < 4; ++j)
    dst[sb + (size_t)(n0 + ty + j * 8) * K + k0 + tx] = f32_bf16(t[tx][ty + j * 8]);
}

// ---------------------------------------------------------------------------
// LayerNorm (f32 in -> bf16 out). One block per row, 256 threads.
// ---------------------------------------------------------------------------
__global__ __launch_bounds__(256) void ln1_kernel(
    const float* __restrict__ x, const float* __restrict__ g,
    const float* __restrict__ b, unsigned short* __restrict__ out) {
  const int row = blockIdx.x;
  const int tid = threadIdx.x;
  const float* xr = x + (size_t)row * Cc;
  float v[4]; float s = 0.f, q = 0.f;
#pragma unroll
  for (int j = 0; j < 4; ++j) { v[j] = xr[tid + j * 256]; s += v[j]; q += v[j] * v[j]; }
#pragma unroll
  for (int m = 1; m <= 32; m <<= 1) { s += __shfl_xor(s, m); q += __shfl_xor(q, m); }
  __shared__ float red[2][4];
  const int w = tid >> 6;
  if ((tid & 63) == 0) { red[0][w] = s; red[1][w] = q; }
  __syncthreads();
  s = red[0][0] + red[0][1] + red[0][2] + red[0][3];
  q = red[1][0] + red[1][1] + red[1][2] + red[1][3];
  const float mean = s * (1.f / Cc);
  const float var = q * (1.f / Cc) - mean * mean;
  const float rstd = rsqrtf(var + 1e-5f);
#pragma unroll
  for (int j = 0; j < 4; ++j) {
    int c = tid + j * 256;
    out[(size_t)row * Cc + c] = f32_bf16((v[j] - mean) * rstd * g[c] + b[c]);
  }
}

// ---------------------------------------------------------------------------
// LN2 + router (all-f32 router math to avoid top-k tie flips).
// ---------------------------------------------------------------------------
__global__ __launch_bounds__(256) void ln2_router_kernel(
    const float* __restrict__ x, const float* __restrict__ g,
    const float* __restrict__ b, const float* __restrict__ rw,
    unsigned short* __restrict__ out, int* __restrict__ tki, float* __restrict__ tkp) {
  const int row = blockIdx.x;
  const int tid = threadIdx.x;
  const float* xr = x + (size_t)row * Cc;
  float v[4]; float s = 0.f, q = 0.f;
#pragma unroll
  for (int j = 0; j < 4; ++j) { v[j] = xr[tid + j * 256]; s += v[j]; q += v[j] * v[j]; }
#pragma unroll
  for (int m = 1; m <= 32; m <<= 1) { s += __shfl_xor(s, m); q += __shfl_xor(q, m); }
  __shared__ float red[2][4];
  const int w = tid >> 6;
  if ((tid & 63) == 0) { red[0][w] = s; red[1][w] = q; }
  __syncthreads();
  s = red[0][0] + red[0][1] + red[0][2] + red[0][3];
  q = red[1][0] + red[1][1] + red[1][2] + red[1][3];
  const float mean = s * (1.f / Cc);
  const float var = q * (1.f / Cc) - mean * mean;
  const float rstd = rsqrtf(var + 1e-5f);
  float lg[8] = {0.f, 0.f, 0.f, 0.f, 0.f, 0.f, 0.f, 0.f};
#pragma unroll
  for (int j = 0; j < 4; ++j) {
    int c = tid + j * 256;
    float nv = (v[j] - mean) * rstd * g[c] + b[c];
    out[(size_t)row * Cc + c] = f32_bf16(nv);
    const float* rwc = rw + c * 8;
#pragma unroll
    for (int e = 0; e < 8; ++e) lg[e] += nv * rwc[e];
  }
#pragma unroll
  for (int m = 1; m <= 32; m <<= 1) {
#pragma unroll
    for (int e = 0; e < 8; ++e) lg[e] += __shfl_xor(lg[e], m);
  }
  __shared__ float rl[4][8];
  if ((tid & 63) == 0) {
#pragma unroll
    for (int e = 0; e < 8; ++e) rl[w][e] = lg[e];
  }
  __syncthreads();
  if (tid == 0) {
    float L[8];
#pragma unroll
    for (int e = 0; e < 8; ++e) L[e] = rl[0][e] + rl[1][e] + rl[2][e] + rl[3][e];
    int i1 = 0;
    for (int e = 1; e < 8; ++e) if (L[e] > L[i1]) i1 = e;
    int i2 = (i1 == 0) ? 1 : 0;
    for (int e = 0; e < 8; ++e) if (e != i1 && L[e] > L[i2]) i2 = e;
    float e2 = expf(L[i2] - L[i1]);
    float inv = 1.f / (1.f + e2);
    tki[row * 2] = i1; tki[row * 2 + 1] = i2;
    tkp[row * 2] = inv; tkp[row * 2 + 1] = e2 * inv;
  }
}

// ---------------------------------------------------------------------------
// Routing: counts -> offsets -> slot assignment (slots compact by expert).
// ---------------------------------------------------------------------------
__global__ __launch_bounds__(256) void count_kernel(
    const int* __restrict__ tki, int* __restrict__ counts) {
  int n = blockIdx.x * 256 + threadIdx.x;
  if (n >= Nc) return;
  atomicAdd(&counts[tki[n * 2]], 1);
  atomicAdd(&counts[tki[n * 2 + 1]], 1);
}

__global__ void scan_kernel(const int* __restrict__ counts,
                            int* __restrict__ eoff, int* __restrict__ cursor) {
  if (threadIdx.x == 0 && blockIdx.x == 0) {
    int s = 0;
    for (int e = 0; e < Ec; ++e) { eoff[e] = s; cursor[e] = s; s += counts[e]; }
    eoff[Ec] = s;
  }
}

__global__ __launch_bounds__(256) void assign_kernel(
    const int* __restrict__ tki, int* __restrict__ cursor,
    int* __restrict__ slot_tok, int* __restrict__ tok2slot) {
  int n = blockIdx.x * 256 + threadIdx.x;
  if (n >= Nc) return;
#pragma unroll
  for (int kk = 0; kk < 2; ++kk) {
    int e = tki[n * 2 + kk];
    int slot = atomicAdd(&cursor[e], 1);
    slot_tok[slot] = n;
    tok2slot[n * 2 + kk] = slot;
  }
}

// ---------------------------------------------------------------------------
// 128x128-tile GEMM, BK=32, double-buffered LDS, 2-phase pipeline:
//   STAGE(next) -> ds_read+MFMA(cur) -> vmcnt(0)+s_barrier (1 barrier/K-step).
// A bf16 [M][lda] (optionally row-gathered), B bf16 pre-transposed [N][K].
// MODE: 0=QKV scatter (V transposed), 1=proj+residual->f32,
//       2=fc gather +gelu->he(bf16), 3=pj->pairout(f32)
// ---------------------------------------------------------------------------
struct GArgs {
  const unsigned short* A;    // bf16
  const unsigned short* Bt;   // bf16 [N][K] (+ e*Bstride)
  const float* bias;          // f32 [N]     (+ e*biasStride)
  int M, N, K, lda;
  size_t Bstride; int biasStride;
  const int* eoff;            // [E+1] slot offsets (MODE 2/3)
  const int* slot_tok;        // slot -> token (MODE 2)
  float* outF;                // MODE 1: out, MODE 3: pairout
  const float* resid;         // MODE 1
  unsigned short* outB;       // MODE 2: he ; MODE 0: q
  unsigned short* outK;       // MODE 0: k
  unsigned short* outV;       // MODE 0: v^T [B,H,D,T]
};

template <int MODE>
__global__ __launch_bounds__(256) void gemm128(GArgs g) {
  const int e = blockIdx.z;
  int s0 = 0, Meff = g.M;
  if constexpr (MODE == 2 || MODE == 3) {
    s0 = g.eoff[e];
    Meff = g.eoff[e + 1] - s0;
  }
  const int row0 = blockIdx.y * 128;
  if (row0 >= Meff) return;
  const int col0 = blockIdx.x * 128;

  __shared__ __align__(16) unsigned short As[2][4096];
  __shared__ __align__(16) unsigned short Bs[2][4096];

  const int tid = threadIdx.x;
  const int lane = tid & 63, w = tid >> 6;
  const int wr = w >> 1, wc = w & 1;
  const int fr = lane & 15, fg = lane >> 4;

  const unsigned short* Bt = g.Bt + (size_t)e * g.Bstride;
  const float* bias = g.bias + (size_t)e * g.biasStride;

  // per-issue global addresses (element offsets), k0 added per step
  size_t aaddr[2], baddr[2];
#pragma unroll
  for (int i = 0; i < 2; ++i) {
    int pos = i * 256 + tid;
    int r = pos >> 2, c8 = (pos & 3) * 8;
    int gr = row0 + r;
    if (gr >= Meff) gr = Meff - 1;            // clamp (partial expert tiles)
    int srcrow;
    if constexpr (MODE == 2) srcrow = g.slot_tok[s0 + gr];
    else if constexpr (MODE == 3) srcrow = s0 + gr;
    else srcrow = gr;
    aaddr[i] = (size_t)srcrow * g.lda + c8;
    baddr[i] = (size_t)(col0 + r) * g.K + c8;
  }

  auto STAGE = [&](int buf, int k0) {
#pragma unroll
    for (int i = 0; i < 2; ++i) {
      GLOAD_LDS16(g.A + aaddr[i] + k0, &As[buf][i * 2048 + w * 512]);
      GLOAD_LDS16(Bt + baddr[i] + k0, &Bs[buf][i * 2048 + w * 512]);
    }
  };

  f32x4 acc[4][4] = {};
  const int nt = g.K / 32;

  STAGE(0, 0);
  SYNC_VM0();
  int cur = 0;

  for (int t = 0; t < nt; ++t) {
    if (t + 1 < nt) STAGE(cur ^ 1, (t + 1) * 32);
    b16v8 af[4], bfr[4];
#pragma unroll
    for (int mi = 0; mi < 4; ++mi)
      af[mi] = *(const b16v8*)&As[cur][(wr * 64 + mi * 16 + fr) * 32 + fg * 8];
#pragma unroll
    for (int ni = 0; ni < 4; ++ni)
      bfr[ni] = *(const b16v8*)&Bs[cur][(wc * 64 + ni * 16 + fr) * 32 + fg * 8];
#pragma unroll
    for (int mi = 0; mi < 4; ++mi)
#pragma unroll
      for (int ni = 0; ni < 4; ++ni)
        acc[mi][ni] = MFMA(af[mi], bfr[ni], acc[mi][ni]);
    if (t + 1 < nt) {
      SYNC_VM0();
      cur ^= 1;
    }
  }

#pragma unroll
  for (int mi = 0; mi < 4; ++mi) {
#pragma unroll
    for (int ni = 0; ni < 4; ++ni) {
#pragma unroll
      for (int rr = 0; rr < 4; ++rr) {
        int row = row0 + wr * 64 + mi * 16 + fg * 4 + rr;  // D: row=(lane>>4)*4+reg
        int col = col0 + wc * 64 + ni * 16 + fr;           // D: col=lane&15
        if (row >= Meff) continue;
        float val = acc[mi][ni][rr] + bias[col];
        if constexpr (MODE == 0) {
          int bb = row >> 11, t = row & (Tc - 1);
          int which = col >> 10, cj = col & (Cc - 1);
          int hd = cj >> 6, d = cj & 63;
          if (which == 0)
            g.outB[(((size_t)(bb * Hc + hd)) * Tc + t) * Dc + d] = f32_bf16(val);
          else if (which == 1)
            g.outK[(((size_t)(bb * Hc + hd)) * Tc + t) * Dc + d] = f32_bf16(val);
          else
            g.outV[(((size_t)(bb * Hc + hd)) * Dc + d) * Tc + t] = f32_bf16(val);
        } else if constexpr (MODE == 1) {
          size_t o = (size_t)row * g.N + col;
          g.outF[o] = val + g.resid[o];
        } else if constexpr (MODE == 2) {
          g.outB[(size_t)(s0 + row) * g.N + col] = f32_bf16(gelu_f(val));
        } else {
          g.outF[(size_t)(s0 + row) * g.N + col] = val;
        }
      }
    }
  }
}

// ---------------------------------------------------------------------------
// Flash-style causal attention. Block = 4 waves, 64 q-rows (16 per wave).
// K tile LDS [kv][d]; V^T tile LDS [d][kv] from pre-transposed vbuf.
// Softmax in exp2 domain (hardware v_exp_f32). P via per-wave LDS round-trip.
// ---------------------------------------------------------------------------
__global__ __launch_bounds__(256) void attn_kernel(
    const unsigned short* __restrict__ q, const unsigned short* __restrict__ k,
    const unsigned short* __restrict__ v, unsigned short* __restrict__ y) {
  const int qt = blockIdx.x, bh = blockIdx.y;
  const int qbase = qt * 64;
  __shared__ __align__(16) unsigned short ldsK[64][72];
  __shared__ __align__(16) unsigned short ldsVT[64][72];     // [d][kv]
  __shared__ __align__(16) unsigned short ldsP[4][16][72];
  const int tid = threadIdx.x, lane = tid & 63, w = tid >> 6;
  const int fr = lane & 15, fg = lane >> 4;
  const size_t base = (size_t)bh * Tc * Dc;
  const int qrow = qbase + w * 16 + fr;
  b16v8 qa0 = *(const b16v8*)(q + base + (size_t)qrow * Dc + fg * 8);
  b16v8 qa1 = *(const b16v8*)(q + base + (size_t)qrow * Dc + 32 + fg * 8);
  float m[4], lsum[4] = {0.f, 0.f, 0.f, 0.f};
#pragma unroll
  for (int r = 0; r < 4; ++r) m[r] = -3.0e38f;
  f32x4 oacc[4] = {};
  constexpr float SC = 0.125f * LOG2E;   // (1/sqrt(64)) * log2(e)

  for (int kb = 0; kb <= qbase; kb += 64) {
    __syncthreads();
#pragma unroll
    for (int i = 0; i < 2; ++i) {
      int pos = i * 256 + tid;
      int r = pos >> 3, cb = (pos & 7) * 8;
      *(uint4*)&ldsK[r][cb]  = *(const uint4*)(k + base + (size_t)(kb + r) * Dc + cb);
      *(uint4*)&ldsVT[r][cb] = *(const uint4*)(v + base + (size_t)r * Tc + kb + cb);
    }
    __syncthreads();

    f32x4 s[4];
#pragma unroll
    for (int ni = 0; ni < 4; ++ni) {
      b16v8 kb0 = *(const b16v8*)&ldsK[ni * 16 + fr][fg * 8];
      b16v8 kb1 = *(const b16v8*)&ldsK[ni * 16 + fr][32 + fg * 8];
      f32x4 z = {};
      z = MFMA(qa0, kb0, z);
      z = MFMA(qa1, kb1, z);
      s[ni] = z;
    }
    const bool diag = (kb == qbase);
#pragma unroll
    for (int ni = 0; ni < 4; ++ni) {
#pragma unroll
      for (int r = 0; r < 4; ++r) {
        float sv = s[ni][r] * SC;       // log2-domain scores
        if (diag) {
          int qr = w * 16 + fg * 4 + r;
          int kc = ni * 16 + fr;
          if (kc > qr) sv = -3.0e38f;
        }
        s[ni][r] = sv;
      }
    }
#pragma unroll
    for (int r = 0; r < 4; ++r) {
      float mx = fmaxf(fmaxf(s[0][r], s[1][r]), fmaxf(s[2][r], s[3][r]));
#pragma unroll
      for (int msk = 1; msk <= 8; msk <<= 1) mx = fmaxf(mx, __shfl_xor(mx, msk));
      float mnew = fmaxf(m[r], mx);
      float alpha = __builtin_amdgcn_exp2f(m[r] - mnew);
      float psum = 0.f;
#pragma unroll
      for (int ni = 0; ni < 4; ++ni) {
        float pp = __builtin_amdgcn_exp2f(s[ni][r] - mnew);
        s[ni][r] = pp;
        psum += pp;
      }
#pragma unroll
      for (int msk = 1; msk <= 8; msk <<= 1) psum += __shfl_xor(psum, msk);
      lsum[r] = lsum[r] * alpha + psum;
      m[r] = mnew;
#pragma unroll
      for (int ni = 0; ni < 4; ++ni) {
        oacc[ni][r] = oacc[ni][r] * alpha;
        ldsP[w][fg * 4 + r][ni * 16 + fr] = f32_bf16(s[ni][r]);
      }
    }
    asm volatile("s_waitcnt lgkmcnt(0)" ::: "memory");
    __builtin_amdgcn_sched_barrier(0);
    b16v8 pa0 = *(const b16v8*)&ldsP[w][fr][fg * 8];
    b16v8 pa1 = *(const b16v8*)&ldsP[w][fr][32 + fg * 8];
#pragma unroll
    for (int ni = 0; ni < 4; ++ni) {
      b16v8 vb0 = *(const b16v8*)&ldsVT[ni * 16 + fr][fg * 8];
      b16v8 vb1 = *(const b16v8*)&ldsVT[ni * 16 + fr][32 + fg * 8];
      oacc[ni] = MFMA(pa0, vb0, oacc[ni]);
      oacc[ni] = MFMA(pa1, vb1, oacc[ni]);
    }
  }

  const int bb = bh >> 4, hh = bh & 15;
#pragma unroll
  for (int r = 0; r < 4; ++r) {
    float rl = __builtin_amdgcn_rcpf(lsum[r]);
#pragma unroll
    for (int ni = 0; ni < 4; ++ni) {
      int t = qbase + w * 16 + fg * 4 + r;
      int d = ni * 16 + fr;
      y[((size_t)(bb * Tc + t)) * Cc + hh * Dc + d] = f32_bf16(oacc[ni][r] * rl);
    }
  }
}

// ---------------------------------------------------------------------------
// Deterministic MoE combine: out[n] += p0*pair[s0] + p1*pair[s1]
// ---------------------------------------------------------------------------
__global__ __launch_bounds__(256) void combine_kernel(
    const float* __restrict__ pair, const float* __restrict__ tkp,
    const int* __restrict__ tok2slot, float* __restrict__ out) {
  const int n = blockIdx.x;
  const int c4 = threadIdx.x * 4;
  const int s0 = tok2slot[n * 2], s1 = tok2slot[n * 2 + 1];
  const float p0 = tkp[n * 2], p1 = tkp[n * 2 + 1];
  float4 a = *(const float4*)&pair[(size_t)s0 * Cc + c4];
  float4 b = *(const float4*)&pair[(size_t)s1 * Cc + c4];
  float4 o = *(float4*)&out[(size_t)n * Cc + c4];
  o.x += p0 * a.x + p1 * b.x;
  o.y += p0 * a.y + p1 * b.y;
  o.z += p0 * a.z + p1 * b.z;
  o.w += p0 * a.w + p1 * b.w;
  *(float4*)&out[(size_t)n * Cc + c4] = o;
}

// ---------------------------------------------------------------------------
extern "C" void kernel_launch(void* const* d_in, const int* in_sizes, int n_in,
                              void* d_out, int out_size, void* d_ws, size_t ws_size,
                              hipStream_t stream) {
  const float* x        = (const float*)d_in[0];
  const float* ln1_g    = (const float*)d_in[1];
  const float* ln1_b    = (const float*)d_in[2];
  const float* ln2_g    = (const float*)d_in[3];
  const float* ln2_b    = (const float*)d_in[4];
  const float* attn_w   = (const float*)d_in[5];
  const float* attn_b   = (const float*)d_in[6];
  const float* proj_w   = (const float*)d_in[7];
  const float* proj_b   = (const float*)d_in[8];
  const float* router_w = (const float*)d_in[9];
  const float* fc_w     = (const float*)d_in[10];
  const float* fc_b     = (const float*)d_in[11];
  const float* pj_w     = (const float*)d_in[12];
  const float* pj_b     = (const float*)d_in[13];
  float* out = (float*)d_out;

  char* ws = (char*)d_ws;
  size_t off = 0;
  auto alloc = [&](size_t bytes) -> void* {
    void* p = ws + off;
    off = (off + bytes + 255) & ~(size_t)255;
    return p;
  };
  unsigned short* attn_wT = (unsigned short*)alloc((size_t)3 * Cc * Cc * 2);      // [3C][C]
  unsigned short* proj_wT = (unsigned short*)alloc((size_t)Cc * Cc * 2);          // [C][C]
  unsigned short* fc_wT   = (unsigned short*)alloc((size_t)Ec * HIDc * Cc * 2);   // [E][HID][C]
  unsigned short* pj_wT   = (unsigned short*)alloc((size_t)Ec * Cc * HIDc * 2);   // [E][C][HID]
  unsigned short* h    = (unsigned short*)alloc((size_t)Nc * Cc * 2);
  unsigned short* qb   = (unsigned short*)alloc((size_t)Nc * Cc * 2);   // [B,H,T,D]
  unsigned short* kbuf = (unsigned short*)alloc((size_t)Nc * Cc * 2);   // [B,H,T,D]
  unsigned short* vbuf = (unsigned short*)alloc((size_t)Nc * Cc * 2);   // [B,H,D,T]
  unsigned short* ybuf = (unsigned short*)alloc((size_t)Nc * Cc * 2);   // [N,C]
  unsigned short* he   = (unsigned short*)alloc((size_t)NPAIR * HIDc * 2);
  float* pairout = (float*)alloc((size_t)NPAIR * Cc * 4);
  int*   tki     = (int*)alloc((size_t)Nc * 2 * 4);
  float* tkp     = (float*)alloc((size_t)Nc * 2 * 4);
  int*   counts  = (int*)alloc(Ec * 4);
  int*   eoff    = (int*)alloc((Ec + 1) * 4);
  int*   cursor  = (int*)alloc(Ec * 4);
  int*   slot_tok= (int*)alloc((size_t)NPAIR * 4);
  int*   tok2slot= (int*)alloc((size_t)Nc * 2 * 4);
  (void)ws_size; (void)in_sizes; (void)n_in; (void)out_size;

  // 0) weight pre-transpose/convert
  convT_kernel<<<dim3(3 * Cc / 32, Cc / 32, 1), 256, 0, stream>>>(attn_w, attn_wT, Cc, 3 * Cc);
  convT_kernel<<<dim3(Cc / 32, Cc / 32, 1), 256, 0, stream>>>(proj_w, proj_wT, Cc, Cc);
  convT_kernel<<<dim3(HIDc / 32, Cc / 32, Ec), 256, 0, stream>>>(fc_w, fc_wT, Cc, HIDc);
  convT_kernel<<<dim3(Cc / 32, HIDc / 32, Ec), 256, 0, stream>>>(pj_w, pj_wT, HIDc, Cc);

  // 1) LN1
  ln1_kernel<<<Nc, 256, 0, stream>>>(x, ln1_g, ln1_b, h);

  // 2) QKV GEMM -> q/k [B,H,T,D], v^T [B,H,D,T]
  {
    GArgs a = {};
    a.A = h; a.Bt = attn_wT; a.bias = attn_b;
    a.M = Nc; a.N = 3 * Cc; a.K = Cc; a.lda = Cc;
    a.outB = qb; a.outK = kbuf; a.outV = vbuf;
    gemm128<0><<<dim3(3 * Cc / 128, Nc / 128, 1), 256, 0, stream>>>(a);
  }

  // 3) causal attention -> y [N,C] bf16
  attn_kernel<<<dim3(Tc / 64, Bc * Hc), 256, 0, stream>>>(qb, kbuf, vbuf, ybuf);

  // 4) proj + residual -> d_out (f32)
  {
    GArgs p = {};
    p.A = ybuf; p.Bt = proj_wT; p.bias = proj_b;
    p.M = Nc; p.N = Cc; p.K = Cc; p.lda = Cc;
    p.outF = out; p.resid = x;
    gemm128<1><<<dim3(Cc / 128, Nc / 128, 1), 256, 0, stream>>>(p);
  }

  // 5) LN2 + router -> h (bf16), top-2
  ln2_router_kernel<<<Nc, 256, 0, stream>>>(out, ln2_g, ln2_b, router_w, h, tki, tkp);

  // 6) routing lists (slot-compacted pairs)
  hipMemsetAsync(counts, 0, Ec * sizeof(int), stream);
  count_kernel<<<(Nc + 255) / 256, 256, 0, stream>>>(tki, counts);
  scan_kernel<<<1, 64, 0, stream>>>(counts, eoff, cursor);
  assign_kernel<<<(Nc + 255) / 256, 256, 0, stream>>>(tki, cursor, slot_tok, tok2slot);

  // 7) fc (all experts concurrent) -> he [NPAIR][HID] bf16 w/ GELU
  {
    GArgs f = {};
    f.A = h; f.Bt = fc_wT; f.bias = fc_b;
    f.M = Nc; f.N = HIDc; f.K = Cc; f.lda = Cc;
    f.Bstride = (size_t)HIDc * Cc; f.biasStride = HIDc;
    f.eoff = eoff; f.slot_tok = slot_tok;
    f.outB = he;
    gemm128<2><<<dim3(HIDc / 128, Nc / 128, Ec), 256, 0, stream>>>(f);
  }

  // 8) pj (all experts concurrent) -> pairout [NPAIR][C] f32 (bias incl.)
  {
    GArgs pj = {};
    pj.A = he; pj.Bt = pj_wT; pj.bias = pj_b;
    pj.M = Nc; pj.N = Cc; pj.K = HIDc; pj.lda = HIDc;
    pj.Bstride = (size_t)Cc * HIDc; pj.biasStride = Cc;
    pj.eoff = eoff;
    pj.outF = pairout;
    gemm128<3><<<dim3(Cc / 128, Nc / 128, Ec), 256, 0, stream>>>(pj);
  }

  // 9) deterministic combine into d_out
  combine_kernel<<<Nc, 256, 0, stream>>>(pairout, tkp, tok2slot, out);
}